// Round 2
// baseline (6865.166 us; speedup 1.0000x reference)
//
#include <hip/hip_runtime.h>
#include <math.h>

#define NA 512
#define NN (NA*NA)
#define COULOMB 14.399645478425668f
#define SQRT_PI 1.7724538509055160273f

__device__ __forceinline__ float rl(float x, int lane) {
    return __int_as_float(__builtin_amdgcn_readlane(__float_as_int(x), lane));
}

// ---------------------------------------------------------------- K1: per-atom
__global__ void k_pre(const float* __restrict__ feats, const float* __restrict__ w,
                      const int* __restrict__ type, const float* __restrict__ hard,
                      const float* __restrict__ sigma,
                      float* __restrict__ chi, float* __restrict__ diag,
                      float* __restrict__ sigA, int N) {
    __shared__ float wl[64];
    int tid = threadIdx.x;
    if (tid < 64) wl[tid] = w[tid];
    __syncthreads();
    int i = blockIdx.x * 256 + tid;
    if (i >= N) return;
    const float4* fp = (const float4*)(feats + (size_t)i * 64);
    float acc = 0.f;
#pragma unroll
    for (int q = 0; q < 16; q++) {
        float4 v = fp[q];
        acc += v.x * wl[4*q] + v.y * wl[4*q+1] + v.z * wl[4*q+2] + v.w * wl[4*q+3];
    }
    chi[i] = acc;
    int t = type[i];
    float s = sigma[t];
    float h = hard[t];
    sigA[i] = s;
    diag[i] = h * h + COULOMB / (SQRT_PI * s);
}

// ---------------------------------------------------------------- fused Cholesky
// One workgroup per molecule. Builds the erf-Coulomb matrix on the fly (round 0),
// factors C = L L^T in 8 blocked rounds entirely within the block.
// LDS: positions/sigma/diag (10KB) + diag tile D (16.6KB) + DT (16KB) + invd.
__global__ void __launch_bounds__(1024) k_chol(const float* __restrict__ pos,
                                               const float* __restrict__ sigA,
                                               const float* __restrict__ diagA,
                                               float* __restrict__ C) {
    const int b = blockIdx.x;
    float* __restrict__ Cb = C + (size_t)b * NN;
    const int tid = threadIdx.x;
    __shared__ float px[NA], py[NA], pz[NA], s2s[NA], dgs[NA];
    __shared__ float D[64 * 65];
    __shared__ float DT[64 * 64];
    __shared__ float invd[64];

    if (tid < NA) {
        px[tid] = pos[((size_t)b * NA + tid) * 3 + 0];
        py[tid] = pos[((size_t)b * NA + tid) * 3 + 1];
        pz[tid] = pos[((size_t)b * NA + tid) * 3 + 2];
        float s = sigA[b * NA + tid];
        s2s[tid] = s * s;
        dgs[tid] = diagA[b * NA + tid];
    }
    __syncthreads();

    const int wv = tid >> 6;
    const int lane = tid & 63;

    for (int j = 0; j < 8; j++) {
        const int jb = j * 64;
        const int m = NA - jb - 64;

        // ---- Phase A: stage diag tile into LDS (generate at j==0)
#pragma unroll
        for (int e = 0; e < 4; e++) {
            int f = e * 1024 + tid;
            int rr = f >> 6, cc = f & 63;
            float v;
            if (j == 0) {
                int gi = jb + rr, gk = jb + cc;
                if (gi == gk) v = dgs[gi];
                else {
                    float dx = px[gi]-px[gk], dy = py[gi]-py[gk], dz = pz[gi]-pz[gk];
                    float d2 = dx*dx + dy*dy + dz*dz;
                    float rinv = rsqrtf(d2);
                    v = COULOMB * erff(d2 * rinv * rsqrtf(2.f*(s2s[gi]+s2s[gk]))) * rinv;
                }
            } else {
                v = Cb[(size_t)(jb + rr) * NA + jb + cc];
            }
            D[rr * 65 + cc] = v;
        }

        // ---- Phase A2: panel row preload into registers (rows owned by tid 64..511)
        float rv[64];
        const int r = tid - 64;
        if (r >= 0 && r < m) {
            const int g = jb + 64 + r;
            if (j == 0) {
#pragma unroll
                for (int k = 0; k < 64; k++) {
                    float dx = px[g]-px[k], dy = py[g]-py[k], dz = pz[g]-pz[k];
                    float d2 = dx*dx + dy*dy + dz*dz;
                    float rinv = rsqrtf(d2);
                    rv[k] = COULOMB * erff(d2 * rinv * rsqrtf(2.f*(s2s[g]+s2s[k]))) * rinv;
                }
            } else {
                const float4* rp = (const float4*)(Cb + (size_t)g * NA + jb);
#pragma unroll
                for (int q = 0; q < 16; q++) {
                    float4 v = rp[q];
                    rv[4*q] = v.x; rv[4*q+1] = v.y; rv[4*q+2] = v.z; rv[4*q+3] = v.w;
                }
            }
        }
        __syncthreads();

        // ---- Phase B: wave 0 register-resident symmetric elimination (no barriers)
        if (tid < 64) {
            const int t = tid;
            float cl[64];
#pragma unroll
            for (int i = 0; i < 64; i++) cl[i] = (i >= t) ? D[i * 65 + t] : D[t * 65 + i];
#pragma unroll
            for (int k = 0; k < 64; k++) {
                float pivot = rl(cl[k], k);
                float invp = 1.0f / pivot;
                float factor = (t > k) ? (cl[k] * invp) : 0.0f;
#pragma unroll
                for (int i = k + 1; i < 64; i++) {
                    float bc = rl(cl[i], k);
                    cl[i] -= bc * factor;
                }
            }
            float rs = 1.0f / sqrtf(cl[t]);
            invd[t] = rs;
#pragma unroll
            for (int i = 0; i < 64; i++)
                if (i >= t) D[i * 65 + t] = cl[i] * rs;
        }
        __syncthreads();

        // ---- Phase B2: build DT (strict lower, zero pad) + store L diag (lower)
#pragma unroll
        for (int e = 0; e < 4; e++) {
            int f = e * 1024 + tid;
            int row = f >> 6, cc = f & 63;
            float v = D[row * 65 + cc];
            DT[row * 64 + cc] = (cc < row) ? v : 0.f;
            if (cc <= row) Cb[(size_t)(jb + row) * NA + jb + cc] = v;
        }
        __syncthreads();

        // ---- Phase C: row-owned trsm, write L21 panel to global
        if (r >= 0 && r < m) {
#pragma unroll
            for (int k = 0; k < 64; k++) {
                float acc = rv[k];
                const float4* Lr = (const float4*)(DT + k * 64);
                const int k4 = k >> 2;
#pragma unroll
                for (int t4 = 0; t4 < k4; t4++) {
                    float4 Lv = Lr[t4];
                    acc -= Lv.x * rv[4*t4] + Lv.y * rv[4*t4+1] + Lv.z * rv[4*t4+2] + Lv.w * rv[4*t4+3];
                }
#pragma unroll
                for (int tt = k4 * 4; tt < k; tt++) acc -= DT[k * 64 + tt] * rv[tt];
                rv[k] = acc * invd[k];
            }
            float4* rp = (float4*)(Cb + (size_t)(jb + 64 + r) * NA + jb);
#pragma unroll
            for (int q = 0; q < 16; q++)
                rp[q] = make_float4(rv[4*q], rv[4*q+1], rv[4*q+2], rv[4*q+3]);
        }
        __threadfence();      // drain stores + invalidate L1 before trailing reads
        __syncthreads();

        // ---- Phase D: trailing update, 64x64 tile per wave-pair, lower tiles only
        const int t = m >> 6;
        const int ntile = t * (t + 1) / 2;
        if (ntile) {
            const int pair = wv >> 1;
            const int half = wv & 1;
            const int lr = lane >> 3, lc = lane & 7;
            for (int idx = pair; idx < ntile; idx += 8) {
                int ti = 0, rem = idx;
                while (rem > ti) { rem -= ti + 1; ti++; }
                const int tj = rem;
                const int gR = jb + 64 + ti * 64 + lr * 8;
                const int gC = jb + 64 + tj * 64 + half * 32 + lc * 4;
                float4 acc[8];
                if (j == 0) {
#pragma unroll
                    for (int rr = 0; rr < 8; rr++) {
                        int gi = gR + rr;
                        float vv[4];
#pragma unroll
                        for (int cc = 0; cc < 4; cc++) {
                            int gk = gC + cc;
                            if (gi == gk) vv[cc] = dgs[gi];
                            else {
                                float dx = px[gi]-px[gk], dy = py[gi]-py[gk], dz = pz[gi]-pz[gk];
                                float d2 = dx*dx + dy*dy + dz*dz;
                                float rinv = rsqrtf(d2);
                                vv[cc] = COULOMB * erff(d2 * rinv * rsqrtf(2.f*(s2s[gi]+s2s[gk]))) * rinv;
                            }
                        }
                        acc[rr] = make_float4(vv[0], vv[1], vv[2], vv[3]);
                    }
                } else {
#pragma unroll
                    for (int rr = 0; rr < 8; rr++)
                        acc[rr] = *(const float4*)(Cb + (size_t)(gR + rr) * NA + gC);
                }
                const float* Arow = Cb + (size_t)gR * NA + jb;
                const float* Brow = Cb + (size_t)gC * NA + jb;
#pragma unroll
                for (int k4 = 0; k4 < 16; k4++) {
                    float4 bj[4];
#pragma unroll
                    for (int cc = 0; cc < 4; cc++)
                        bj[cc] = *(const float4*)(Brow + (size_t)cc * NA + k4 * 4);
#pragma unroll
                    for (int rr = 0; rr < 8; rr++) {
                        float4 ai = *(const float4*)(Arow + (size_t)rr * NA + k4 * 4);
                        acc[rr].x -= ai.x*bj[0].x + ai.y*bj[0].y + ai.z*bj[0].z + ai.w*bj[0].w;
                        acc[rr].y -= ai.x*bj[1].x + ai.y*bj[1].y + ai.z*bj[1].z + ai.w*bj[1].w;
                        acc[rr].z -= ai.x*bj[2].x + ai.y*bj[2].y + ai.z*bj[2].z + ai.w*bj[2].w;
                        acc[rr].w -= ai.x*bj[3].x + ai.y*bj[3].y + ai.z*bj[3].z + ai.w*bj[3].w;
                    }
                }
#pragma unroll
                for (int rr = 0; rr < 8; rr++)
                    *(float4*)(Cb + (size_t)(gR + rr) * NA + gC) = acc[rr];
            }
        }
        __threadfence();      // make trailing stores visible to next round's reads
        __syncthreads();
    }
}

// ------------------------------------------- K5: solves + mu + q + energy (identity)
__global__ void __launch_bounds__(512) k_solve(const float* __restrict__ C,
                                               const float* __restrict__ chiA,
                                               const float* __restrict__ Qtot,
                                               float* __restrict__ out, int B) {
    int b = blockIdx.x;
    const float* Cb = C + (size_t)b * NN;
    int tid = threadIdx.x;
    __shared__ float D[64 * 65];
    __shared__ float v1[NA], v2[NA];
    __shared__ float tv1[64], tv2[64];
    __shared__ float pb[2][8][64];
    __shared__ float red[16];
    __shared__ float muS;

    v1[tid] = chiA[b * NA + tid];   // RHS1 = chi  (x1 = C^-1 chi)
    v2[tid] = 1.0f;                 // RHS2 = ones (x2 = C^-1 1)

    // -------- forward: y = L^-1 r
    for (int j = 0; j < 8; j++) {
        int jb = j * 64;
        __syncthreads();
#pragma unroll
        for (int e = 0; e < 8; e++) {
            int f = e * 512 + tid;
            int row = f >> 6, cc = f & 63;
            D[row * 65 + cc] = Cb[(size_t)(jb + row) * NA + jb + cc];
        }
        int i = tid >> 3, l8 = tid & 7;
        float pa1 = 0.f, pa2 = 0.f;
        for (int cx = l8; cx < jb; cx += 8) {
            float Lv = Cb[(size_t)(jb + i) * NA + cx];
            pa1 += Lv * v1[cx]; pa2 += Lv * v2[cx];
        }
        pa1 += __shfl_xor(pa1, 1); pa2 += __shfl_xor(pa2, 1);
        pa1 += __shfl_xor(pa1, 2); pa2 += __shfl_xor(pa2, 2);
        pa1 += __shfl_xor(pa1, 4); pa2 += __shfl_xor(pa2, 4);
        if (l8 == 0) { tv1[i] = v1[jb + i] - pa1; tv2[i] = v2[jb + i] - pa2; }
        __syncthreads();
        if (tid < 128) {
            int lane = tid & 63;
            float* vv = (tid < 64) ? v1 : v2;
            const float* tv = (tid < 64) ? tv1 : tv2;
            float val = tv[lane];
            float idg = 1.0f / D[lane * 65 + lane];
#pragma unroll
            for (int k = 0; k < 64; k++) {
                float yk = rl(val, k) * rl(idg, k);
                if (lane == k) vv[jb + k] = yk;
                float lv = (lane > k) ? D[lane * 65 + k] : 0.f;
                val -= lv * yk;
            }
        }
    }

    // -------- backward: x = L^-T y
    for (int j = 7; j >= 0; j--) {
        int jb = j * 64;
        __syncthreads();
#pragma unroll
        for (int e = 0; e < 8; e++) {
            int f = e * 512 + tid;
            int row = f >> 6, cc = f & 63;
            D[row * 65 + cc] = Cb[(size_t)(jb + row) * NA + jb + cc];
        }
        int trp = tid >> 6, i2 = tid & 63;
        float px1 = 0.f, px2 = 0.f;
        for (int gt = jb + 64 + trp; gt < NA; gt += 8) {
            float Lv = Cb[(size_t)gt * NA + jb + i2];
            px1 += Lv * v1[gt]; px2 += Lv * v2[gt];
        }
        pb[0][trp][i2] = px1; pb[1][trp][i2] = px2;
        __syncthreads();
        if (tid < 64) {
            float s = 0.f;
#pragma unroll
            for (int tr = 0; tr < 8; tr++) s += pb[0][tr][tid];
            tv1[tid] = v1[jb + tid] - s;
        } else if (tid < 128) {
            int l = tid - 64;
            float s = 0.f;
#pragma unroll
            for (int tr = 0; tr < 8; tr++) s += pb[1][tr][l];
            tv2[l] = v2[jb + l] - s;
        }
        __syncthreads();
        if (tid < 128) {
            int lane = tid & 63;
            float* vv = (tid < 64) ? v1 : v2;
            const float* tv = (tid < 64) ? tv1 : tv2;
            float val = tv[lane];
            float idg = 1.0f / D[lane * 65 + lane];
#pragma unroll
            for (int k = 63; k >= 0; k--) {
                float xk = rl(val, k) * rl(idg, k);
                if (lane == k) vv[jb + k] = xk;
                float lv = (lane < k) ? D[k * 65 + lane] : 0.f;
                val -= lv * xk;
            }
        }
    }
    __syncthreads();

    // -------- mu, q, and energy via e = 0.5*chi'q - 0.5*mu*Q
    float s1p = v1[tid], s2p = v2[tid];
#pragma unroll
    for (int off = 1; off < 64; off <<= 1) {
        s1p += __shfl_xor(s1p, off);
        s2p += __shfl_xor(s2p, off);
    }
    if ((tid & 63) == 0) { red[tid >> 6] = s1p; red[8 + (tid >> 6)] = s2p; }
    __syncthreads();
    if (tid == 0) {
        float s1 = 0.f, s2 = 0.f;
#pragma unroll
        for (int wv = 0; wv < 8; wv++) { s1 += red[wv]; s2 += red[8 + wv]; }
        muS = -(Qtot[b] + s1) / s2;
    }
    __syncthreads();
    float mu = muS;
    float qv = -v1[tid] - mu * v2[tid];
    out[B + (size_t)b * NA + tid] = qv;

    float eacc = chiA[b * NA + tid] * qv;
#pragma unroll
    for (int off = 1; off < 64; off <<= 1) eacc += __shfl_xor(eacc, off);
    __syncthreads();
    if ((tid & 63) == 0) red[tid >> 6] = eacc;
    __syncthreads();
    if (tid == 0) {
        float e = 0.f;
#pragma unroll
        for (int wv = 0; wv < 8; wv++) e += red[wv];
        out[b] = 0.5f * e - 0.5f * mu * Qtot[b];
    }
}

// ---------------------------------------------------------------- host launch
extern "C" void kernel_launch(void* const* d_in, const int* in_sizes, int n_in,
                              void* d_out, int out_size, void* d_ws, size_t ws_size,
                              hipStream_t stream) {
    const int B = in_sizes[3];          // 128 molecules
    const int N = in_sizes[2];          // 65536 atoms
    const float* feats = (const float*)d_in[0];
    const float* pos   = (const float*)d_in[1];
    const int*   type  = (const int*)d_in[2];
    const float* Qt    = (const float*)d_in[3];
    const float* w     = (const float*)d_in[4];
    const float* hard  = (const float*)d_in[5];
    const float* sig   = (const float*)d_in[6];
    float* out = (float*)d_out;
    float* ws  = (float*)d_ws;

    float* C    = ws;                       // B * 512 * 512
    float* chi  = ws + (size_t)B * NN;      // N
    float* diag = chi + N;                  // N
    float* sigA = diag + N;                 // N

    k_pre<<<(N + 255) / 256, 256, 0, stream>>>(feats, w, type, hard, sig, chi, diag, sigA, N);
    k_chol<<<B, 1024, 0, stream>>>(pos, sigA, diag, C);
    k_solve<<<B, 512, 0, stream>>>(C, chi, Qt, out, B);
}

// Round 3
// 810.838 us; speedup vs baseline: 8.4668x; 8.4668x over previous
//
#include <hip/hip_runtime.h>
#include <math.h>

#define NA 512
#define NN (NA*NA)
#define COULOMB 14.399645478425668f
#define SQRT_PI 1.7724538509055160273f

__device__ __forceinline__ float rl(float x, int lane) {
    return __int_as_float(__builtin_amdgcn_readlane(__float_as_int(x), lane));
}

__device__ __forceinline__ float pair_val(float dx, float dy, float dz,
                                          float s2i, float s2k) {
    float d2 = dx*dx + dy*dy + dz*dz;
    float rinv = rsqrtf(d2);
    return COULOMB * erff(d2 * rinv * rsqrtf(2.f * (s2i + s2k))) * rinv;
}

// ---------------------------------------------------------------- K1: per-atom
__global__ void k_pre(const float* __restrict__ feats, const float* __restrict__ w,
                      const int* __restrict__ type, const float* __restrict__ hard,
                      const float* __restrict__ sigma,
                      float* __restrict__ chi, float* __restrict__ diag,
                      float* __restrict__ sigA, int N) {
    __shared__ float wl[64];
    int tid = threadIdx.x;
    if (tid < 64) wl[tid] = w[tid];
    __syncthreads();
    int i = blockIdx.x * 256 + tid;
    if (i >= N) return;
    const float4* fp = (const float4*)(feats + (size_t)i * 64);
    float acc = 0.f;
#pragma unroll
    for (int q = 0; q < 16; q++) {
        float4 v = fp[q];
        acc += v.x * wl[4*q] + v.y * wl[4*q+1] + v.z * wl[4*q+2] + v.w * wl[4*q+3];
    }
    chi[i] = acc;
    int t = type[i];
    float s = sigma[t];
    float h = hard[t];
    sigA[i] = s;
    diag[i] = h * h + COULOMB / (SQRT_PI * s);
}

// ------------------------------------------- K2: diag factor + panel trsm (step j)
// 512 threads, cap 256 VGPR (2 waves/SIMD) so rv[64]/cl[64] stay in registers.
__global__ void __launch_bounds__(512, 2) k_panel(const float* __restrict__ pos,
                                                  const float* __restrict__ sigA,
                                                  const float* __restrict__ diagA,
                                                  float* __restrict__ C, const int j) {
    const int b = blockIdx.x;
    float* __restrict__ Cb = C + (size_t)b * NN;
    const int jb = j * 64;
    const int m = NA - jb - 64;
    const int tid = threadIdx.x;
    __shared__ float D[64 * 65];
    __shared__ float DT[64 * 64];
    __shared__ float invd[64];
    __shared__ float px[NA], py[NA], pz[NA], s2s[NA];

    if (j == 0) {
        if (tid < NA) {
            px[tid] = pos[((size_t)b * NA + tid) * 3 + 0];
            py[tid] = pos[((size_t)b * NA + tid) * 3 + 1];
            pz[tid] = pos[((size_t)b * NA + tid) * 3 + 2];
            float s = sigA[b * NA + tid];
            s2s[tid] = s * s;
        }
        __syncthreads();
    }

    // ---- Phase A: stage diag tile into LDS (generate at j==0)
#pragma unroll
    for (int e = 0; e < 8; e++) {
        int f = e * 512 + tid;
        int rr = f >> 6, cc = f & 63;
        float v;
        if (j == 0) {
            if (rr == cc) v = diagA[b * NA + rr];
            else v = pair_val(px[rr]-px[cc], py[rr]-py[cc], pz[rr]-pz[cc], s2s[rr], s2s[cc]);
        } else {
            v = Cb[(size_t)(jb + rr) * NA + jb + cc];
        }
        D[rr * 65 + cc] = v;
    }

    // ---- Phase A2: panel row preload into registers (rows on tid 64..511)
    float rv[64];
    const int r = tid - 64;
    if (r >= 0 && r < m) {
        const int g = jb + 64 + r;
        if (j == 0) {
#pragma unroll
            for (int k = 0; k < 64; k++)
                rv[k] = pair_val(px[g]-px[k], py[g]-py[k], pz[g]-pz[k], s2s[g], s2s[k]);
        } else {
            const float4* rp = (const float4*)(Cb + (size_t)g * NA + jb);
#pragma unroll
            for (int q = 0; q < 16; q++) {
                float4 v = rp[q];
                rv[4*q] = v.x; rv[4*q+1] = v.y; rv[4*q+2] = v.z; rv[4*q+3] = v.w;
            }
        }
    }
    __syncthreads();

    // ---- Phase B: wave 0 register-resident symmetric elimination (no barriers)
    if (tid < 64) {
        const int t = tid;
        float cl[64];
#pragma unroll
        for (int i = 0; i < 64; i++) cl[i] = (i >= t) ? D[i * 65 + t] : D[t * 65 + i];
#pragma unroll
        for (int k = 0; k < 64; k++) {
            float pivot = rl(cl[k], k);
            float invp = 1.0f / pivot;
            float factor = (t > k) ? (cl[k] * invp) : 0.0f;
#pragma unroll
            for (int i = k + 1; i < 64; i++) {
                float bc = rl(cl[i], k);
                cl[i] -= bc * factor;
            }
        }
        float rs = 1.0f / sqrtf(cl[t]);
        invd[t] = rs;
#pragma unroll
        for (int i = 0; i < 64; i++)
            if (i >= t) D[i * 65 + t] = cl[i] * rs;
    }
    __syncthreads();

    // ---- Phase B2: build DT (strict lower, zero pad) + store L diag (lower)
#pragma unroll
    for (int e = 0; e < 8; e++) {
        int f = e * 512 + tid;
        int row = f >> 6, cc = f & 63;
        float v = D[row * 65 + cc];
        DT[row * 64 + cc] = (cc < row) ? v : 0.f;
        if (cc <= row) Cb[(size_t)(jb + row) * NA + jb + cc] = v;
    }
    __syncthreads();

    // ---- Phase C: row-owned trsm, write L21 panel to global
    if (r >= 0 && r < m) {
#pragma unroll
        for (int k = 0; k < 64; k++) {
            float acc = rv[k];
            const float4* Lr = (const float4*)(DT + k * 64);
            const int k4 = k >> 2;
#pragma unroll
            for (int t4 = 0; t4 < k4; t4++) {
                float4 Lv = Lr[t4];
                acc -= Lv.x * rv[4*t4] + Lv.y * rv[4*t4+1] + Lv.z * rv[4*t4+2] + Lv.w * rv[4*t4+3];
            }
#pragma unroll
            for (int tt = k4 * 4; tt < k; tt++) acc -= DT[k * 64 + tt] * rv[tt];
            rv[k] = acc * invd[k];
        }
        float4* rp = (float4*)(Cb + (size_t)(jb + 64 + r) * NA + jb);
#pragma unroll
        for (int q = 0; q < 16; q++)
            rp[q] = make_float4(rv[4*q], rv[4*q+1], rv[4*q+2], rv[4*q+3]);
    }
}

// ------------------------------------------- K3: trailing update (step j)
// 128x128 supertile, 256 threads, 8x8 scalar acc. GEN=true (j==0) generates the
// tile with erf instead of RMW-reading it. Stride-65 LDS + col=cg+16*cc mapping:
// B reads hit 16 distinct banks (conflict-free); A reads are 4-address broadcasts.
template<bool GEN>
__global__ void __launch_bounds__(256, 3) k_trail(float* __restrict__ C,
                                                  const float* __restrict__ pos,
                                                  const float* __restrict__ sigA,
                                                  const float* __restrict__ diagA,
                                                  const int j) {
    const int b = blockIdx.y;
    float* __restrict__ Cb = C + (size_t)b * NN;
    const int jb = j * 64;
    const int m = NA - jb - 64;
    int t = blockIdx.x;
    int RI = 0;
    while (t >= RI + 1) { t -= RI + 1; RI++; }
    const int RJ = t;
    const int RB = RI * 128, CB = RJ * 128;
    const int vr = min(128, m - RB);
    const int vc = min(128, m - CB);
    const int tid = threadIdx.x;
    const int rg = tid >> 4, cg = tid & 15;

    __shared__ float As[128 * 65];
    __shared__ float Bs[128 * 65];

    float acc[8][8];

    if (GEN) {
        __shared__ float pAx[128], pAy[128], pAz[128], sA[128], dA[128];
        __shared__ float pBx[128], pBy[128], pBz[128], sB[128];
        if (tid < 128) {
            if (RB + tid < m) {
                int ga = b * NA + jb + 64 + RB + tid;
                pAx[tid] = pos[(size_t)ga * 3 + 0];
                pAy[tid] = pos[(size_t)ga * 3 + 1];
                pAz[tid] = pos[(size_t)ga * 3 + 2];
                float s = sigA[ga]; sA[tid] = s * s;
                dA[tid] = diagA[ga];
            }
        } else {
            int u = tid - 128;
            if (CB + u < m) {
                int gb = b * NA + jb + 64 + CB + u;
                pBx[u] = pos[(size_t)gb * 3 + 0];
                pBy[u] = pos[(size_t)gb * 3 + 1];
                pBz[u] = pos[(size_t)gb * 3 + 2];
                float s = sigA[gb]; sB[u] = s * s;
            }
        }
        __syncthreads();
#pragma unroll
        for (int rr = 0; rr < 8; rr++) {
            int row = rg * 8 + rr;
#pragma unroll
            for (int cc = 0; cc < 8; cc++) {
                int col = cg + 16 * cc;
                if (RB + row == CB + col)
                    acc[rr][cc] = dA[row];
                else
                    acc[rr][cc] = pair_val(pAx[row]-pBx[col], pAy[row]-pBy[col],
                                           pAz[row]-pBz[col], sA[row], sB[col]);
            }
        }
        __syncthreads();   // pA/pB LDS dead after this; As/Bs staging follows
    } else {
        const int GRB = jb + 64 + RB, GCB = jb + 64 + CB;
#pragma unroll
        for (int rr = 0; rr < 8; rr++) {
            int row = rg * 8 + rr;
#pragma unroll
            for (int cc = 0; cc < 8; cc++) {
                int col = cg + 16 * cc;
                acc[rr][cc] = (row < vr && col < vc)
                    ? Cb[(size_t)(GRB + row) * NA + GCB + col] : 0.f;
            }
        }
    }

    // ---- stage the two panel slabs (L21 rows) into LDS, stride 65
    const float* Pan = Cb + (size_t)(jb + 64) * NA + jb;
#pragma unroll
    for (int e = 0; e < 8; e++) {
        int f = e * 256 + tid;
        int row = f >> 4, s = f & 15;
        float4 v = make_float4(0.f, 0.f, 0.f, 0.f);
        if (row < vr) v = *(const float4*)(Pan + (size_t)(RB + row) * NA + s * 4);
        As[row * 65 + s * 4 + 0] = v.x;
        As[row * 65 + s * 4 + 1] = v.y;
        As[row * 65 + s * 4 + 2] = v.z;
        As[row * 65 + s * 4 + 3] = v.w;
        float4 u = make_float4(0.f, 0.f, 0.f, 0.f);
        if (row < vc) u = *(const float4*)(Pan + (size_t)(CB + row) * NA + s * 4);
        Bs[row * 65 + s * 4 + 0] = u.x;
        Bs[row * 65 + s * 4 + 1] = u.y;
        Bs[row * 65 + s * 4 + 2] = u.z;
        Bs[row * 65 + s * 4 + 3] = u.w;
    }
    __syncthreads();

    // ---- K=64 rank-update, 8x8 per thread
#pragma unroll 4
    for (int k = 0; k < 64; k++) {
        float ai[8], bj[8];
#pragma unroll
        for (int rr = 0; rr < 8; rr++) ai[rr] = As[(rg * 8 + rr) * 65 + k];
#pragma unroll
        for (int cc = 0; cc < 8; cc++) bj[cc] = Bs[(cg + 16 * cc) * 65 + k];
#pragma unroll
        for (int rr = 0; rr < 8; rr++)
#pragma unroll
            for (int cc = 0; cc < 8; cc++)
                acc[rr][cc] = fmaf(-ai[rr], bj[cc], acc[rr][cc]);
    }

    // ---- store (garbage above the diagonal is fine: nothing reads the upper)
    const int GRB = jb + 64 + RB, GCB = jb + 64 + CB;
#pragma unroll
    for (int rr = 0; rr < 8; rr++) {
        int row = rg * 8 + rr;
        if (row < vr) {
#pragma unroll
            for (int cc = 0; cc < 8; cc++) {
                int col = cg + 16 * cc;
                if (col < vc)
                    Cb[(size_t)(GRB + row) * NA + GCB + col] = acc[rr][cc];
            }
        }
    }
}

// ------------------------------------------- K4: solves + mu + q + energy identity
__global__ void __launch_bounds__(512) k_solve(const float* __restrict__ C,
                                               const float* __restrict__ chiA,
                                               const float* __restrict__ Qtot,
                                               float* __restrict__ out, int B) {
    int b = blockIdx.x;
    const float* Cb = C + (size_t)b * NN;
    int tid = threadIdx.x;
    __shared__ float D[64 * 65];
    __shared__ float v1[NA], v2[NA];
    __shared__ float tv1[64], tv2[64];
    __shared__ float pb[2][8][64];
    __shared__ float red[16];
    __shared__ float muS;

    v1[tid] = chiA[b * NA + tid];
    v2[tid] = 1.0f;

    // -------- forward: y = L^-1 r
    for (int j = 0; j < 8; j++) {
        int jb = j * 64;
        __syncthreads();
#pragma unroll
        for (int e = 0; e < 8; e++) {
            int f = e * 512 + tid;
            int row = f >> 6, cc = f & 63;
            D[row * 65 + cc] = Cb[(size_t)(jb + row) * NA + jb + cc];
        }
        int i = tid >> 3, l8 = tid & 7;
        float pa1 = 0.f, pa2 = 0.f;
        for (int cx = l8; cx < jb; cx += 8) {
            float Lv = Cb[(size_t)(jb + i) * NA + cx];
            pa1 += Lv * v1[cx]; pa2 += Lv * v2[cx];
        }
        pa1 += __shfl_xor(pa1, 1); pa2 += __shfl_xor(pa2, 1);
        pa1 += __shfl_xor(pa1, 2); pa2 += __shfl_xor(pa2, 2);
        pa1 += __shfl_xor(pa1, 4); pa2 += __shfl_xor(pa2, 4);
        if (l8 == 0) { tv1[i] = v1[jb + i] - pa1; tv2[i] = v2[jb + i] - pa2; }
        __syncthreads();
        if (tid < 128) {
            int lane = tid & 63;
            float* vv = (tid < 64) ? v1 : v2;
            const float* tv = (tid < 64) ? tv1 : tv2;
            float val = tv[lane];
            float idg = 1.0f / D[lane * 65 + lane];
#pragma unroll
            for (int k = 0; k < 64; k++) {
                float yk = rl(val, k) * rl(idg, k);
                if (lane == k) vv[jb + k] = yk;
                float lv = (lane > k) ? D[lane * 65 + k] : 0.f;
                val -= lv * yk;
            }
        }
    }

    // -------- backward: x = L^-T y
    for (int j = 7; j >= 0; j--) {
        int jb = j * 64;
        __syncthreads();
#pragma unroll
        for (int e = 0; e < 8; e++) {
            int f = e * 512 + tid;
            int row = f >> 6, cc = f & 63;
            D[row * 65 + cc] = Cb[(size_t)(jb + row) * NA + jb + cc];
        }
        int trp = tid >> 6, i2 = tid & 63;
        float px1 = 0.f, px2 = 0.f;
        for (int gt = jb + 64 + trp; gt < NA; gt += 8) {
            float Lv = Cb[(size_t)gt * NA + jb + i2];
            px1 += Lv * v1[gt]; px2 += Lv * v2[gt];
        }
        pb[0][trp][i2] = px1; pb[1][trp][i2] = px2;
        __syncthreads();
        if (tid < 64) {
            float s = 0.f;
#pragma unroll
            for (int tr = 0; tr < 8; tr++) s += pb[0][tr][tid];
            tv1[tid] = v1[jb + tid] - s;
        } else if (tid < 128) {
            int l = tid - 64;
            float s = 0.f;
#pragma unroll
            for (int tr = 0; tr < 8; tr++) s += pb[1][tr][l];
            tv2[l] = v2[jb + l] - s;
        }
        __syncthreads();
        if (tid < 128) {
            int lane = tid & 63;
            float* vv = (tid < 64) ? v1 : v2;
            const float* tv = (tid < 64) ? tv1 : tv2;
            float val = tv[lane];
            float idg = 1.0f / D[lane * 65 + lane];
#pragma unroll
            for (int k = 63; k >= 0; k--) {
                float xk = rl(val, k) * rl(idg, k);
                if (lane == k) vv[jb + k] = xk;
                float lv = (lane < k) ? D[k * 65 + lane] : 0.f;
                val -= lv * xk;
            }
        }
    }
    __syncthreads();

    // -------- mu, q, energy: e = 0.5*chi'q - 0.5*mu*Q  (from C q = -chi - mu*1)
    float s1p = v1[tid], s2p = v2[tid];
#pragma unroll
    for (int off = 1; off < 64; off <<= 1) {
        s1p += __shfl_xor(s1p, off);
        s2p += __shfl_xor(s2p, off);
    }
    if ((tid & 63) == 0) { red[tid >> 6] = s1p; red[8 + (tid >> 6)] = s2p; }
    __syncthreads();
    if (tid == 0) {
        float s1 = 0.f, s2 = 0.f;
#pragma unroll
        for (int wv = 0; wv < 8; wv++) { s1 += red[wv]; s2 += red[8 + wv]; }
        muS = -(Qtot[b] + s1) / s2;
    }
    __syncthreads();
    float mu = muS;
    float qv = -v1[tid] - mu * v2[tid];
    out[B + (size_t)b * NA + tid] = qv;

    float eacc = chiA[b * NA + tid] * qv;
#pragma unroll
    for (int off = 1; off < 64; off <<= 1) eacc += __shfl_xor(eacc, off);
    __syncthreads();
    if ((tid & 63) == 0) red[tid >> 6] = eacc;
    __syncthreads();
    if (tid == 0) {
        float e = 0.f;
#pragma unroll
        for (int wv = 0; wv < 8; wv++) e += red[wv];
        out[b] = 0.5f * e - 0.5f * mu * Qtot[b];
    }
}

// ---------------------------------------------------------------- host launch
extern "C" void kernel_launch(void* const* d_in, const int* in_sizes, int n_in,
                              void* d_out, int out_size, void* d_ws, size_t ws_size,
                              hipStream_t stream) {
    const int B = in_sizes[3];          // 128 molecules
    const int N = in_sizes[2];          // 65536 atoms
    const float* feats = (const float*)d_in[0];
    const float* pos   = (const float*)d_in[1];
    const int*   type  = (const int*)d_in[2];
    const float* Qt    = (const float*)d_in[3];
    const float* w     = (const float*)d_in[4];
    const float* hard  = (const float*)d_in[5];
    const float* sig   = (const float*)d_in[6];
    float* out = (float*)d_out;
    float* ws  = (float*)d_ws;

    float* C    = ws;                       // B * 512 * 512
    float* chi  = ws + (size_t)B * NN;      // N
    float* diag = chi + N;                  // N
    float* sigA = diag + N;                 // N

    k_pre<<<(N + 255) / 256, 256, 0, stream>>>(feats, w, type, hard, sig, chi, diag, sigA, N);

    static const int tilesJ[7] = {10, 6, 6, 3, 3, 1, 1};
    for (int j = 0; j < 8; j++) {
        k_panel<<<B, 512, 0, stream>>>(pos, sigA, diag, C, j);
        if (j < 7) {
            if (j == 0)
                k_trail<true><<<dim3(tilesJ[j], B), 256, 0, stream>>>(C, pos, sigA, diag, j);
            else
                k_trail<false><<<dim3(tilesJ[j], B), 256, 0, stream>>>(C, pos, sigA, diag, j);
        }
    }
    k_solve<<<B, 512, 0, stream>>>(C, chi, Qt, out, B);
}